// Round 15
// baseline (122.074 us; speedup 1.0000x reference)
//
#include <hip/hip_runtime.h>
#include <hip/hip_bf16.h>
#include <stdint.h>

#define NB 8
#define NSQ 1024
#define NSK 1024
#define NHID 512
#define NHEAD 4
#define NDH 128

typedef __attribute__((ext_vector_type(8))) short short8;
typedef __attribute__((ext_vector_type(4))) float f32x4;
typedef __attribute__((ext_vector_type(4))) int i32x4;

__device__ __forceinline__ unsigned short f2b(float f) {
  unsigned int u = __builtin_bit_cast(unsigned int, f);
  u = u + 0x7FFFu + ((u >> 16) & 1u);
  return (unsigned short)(u >> 16);
}

__device__ __forceinline__ float b2f(unsigned short s) {
  unsigned int u = ((unsigned int)s) << 16;
  return __builtin_bit_cast(float, u);
}

__device__ __forceinline__ short8 pack8v(f32x4 a, f32x4 b) {
  short8 o;
  o[0] = (short)f2b(a.x); o[1] = (short)f2b(a.y);
  o[2] = (short)f2b(a.z); o[3] = (short)f2b(a.w);
  o[4] = (short)f2b(b.x); o[5] = (short)f2b(b.y);
  o[6] = (short)f2b(b.z); o[7] = (short)f2b(b.w);
  return o;
}

// async global->LDS, 16B per lane; lds dest = wave-uniform base + lane*16
__device__ __forceinline__ void gl2lds16(const unsigned short* g, unsigned short* l) {
  __builtin_amdgcn_global_load_lds(
      (const __attribute__((address_space(1))) void*)g,
      (__attribute__((address_space(3))) void*)l, 16, 0, 0);
}

// ---------------- K0: fused f32->panel convert + mask bit-pack ---------------
__global__ __launch_bounds__(256) void cvt_pack(
    const float* __restrict__ dec, const float* __restrict__ mem,
    const float* __restrict__ Wq, const float* __restrict__ Wk,
    const float* __restrict__ Wv, const int* __restrict__ mask,
    unsigned short* __restrict__ decB, unsigned short* __restrict__ memB,
    unsigned short* __restrict__ WB, unsigned int* __restrict__ mw) {
  const int bid = blockIdx.x, tid = threadIdx.x;
  if (bid >= 4480) {
    int w = (bid - 4480) * 256 + tid;  // word index, 262144 total
    const int* src = mask + (size_t)w * 32;
    unsigned int bits = 0;
#pragma unroll
    for (int j = 0; j < 32; j += 4) {
      i32x4 v = *(const i32x4*)(src + j);
      bits |= (v.x ? 1u << j : 0u) | (v.y ? 1u << (j + 1) : 0u) |
              (v.z ? 1u << (j + 2) : 0u) | (v.w ? 1u << (j + 3) : 0u);
    }
    int row = w >> 5, wi = w & 31;
    mw[(size_t)row * 32 + ((wi & 3) * 8 + (wi >> 2))] = bits;
    return;
  }
  const float* src;
  unsigned short* dst;
  int base_row;
  if (bid < 2048) { src = dec; dst = decB; base_row = bid * 4; }
  else if (bid < 4096) { src = mem; dst = memB; base_row = (bid - 2048) * 4; }
  else {
    int w = bid - 4096;          // 0..383
    int wi = w >> 7;             // which weight
    src = (wi == 0) ? Wq : (wi == 1) ? Wk : Wv;
    dst = WB + (size_t)wi * 262144;
    base_row = (w & 127) * 4;
  }
  const int row = base_row + (tid >> 6);
  const int kpos = (tid & 63) * 8;
  const float* s = src + (size_t)row * 512 + kpos;
  f32x4 a0 = *(const f32x4*)s;
  f32x4 a1 = *(const f32x4*)(s + 4);
  const int mt = row >> 7, kt = kpos >> 6, pr = row & 127, c = (kpos & 63) >> 3;
  *(short8*)&dst[(size_t)(mt * 8 + kt) * 8192 + pr * 64 + ((c ^ (pr & 7)) * 8)] =
      pack8v(a0, a1);
}

// ---------------- K1: all 3 projection GEMMs, one launch (128,4,3) -----------
// 64x128 tiles: 3 blocks/CU (48KB LDS) so the per-kt barrier drain overlaps.
__global__ __launch_bounds__(256) void proj_gemm_all(
    const unsigned short* __restrict__ decB, const unsigned short* __restrict__ memB,
    const unsigned short* __restrict__ WB, unsigned short* __restrict__ Cb) {
  __shared__ unsigned short tA[2][4096];   // 16KB: 64 rows x 64 k, dbuf
  __shared__ unsigned short tB[2][8192];   // 32KB: 128 rows x 64 k, dbuf
  const int z = blockIdx.z;
  const int mt = blockIdx.x, h = blockIdx.y;  // mt: 64-row tile index (0..127)
  const unsigned short* A = (z == 0) ? decB : memB;
  const unsigned short* W = WB + (size_t)z * 262144;
  unsigned short* C = Cb + (size_t)z * 4194304;
  const bool tr = (z == 2);
  const int tid = threadIdx.x, lane = tid & 63, wave = tid >> 6;
  const int wm = (wave & 1) * 32, wn = (wave >> 1) * 64;
  const int r15 = lane & 15, hi = lane >> 4;

  auto stage = [&](int kt, int sel) {
    const unsigned short* ap =
        A + (size_t)((mt >> 1) * 8 + kt) * 8192 + (mt & 1) * 4096;
#pragma unroll
    for (int i = 0; i < 2; ++i) {
      int ci = i * 4 + wave;
      gl2lds16(ap + ci * 512 + lane * 8, &tA[sel][ci * 512 + lane * 8]);
    }
#pragma unroll
    for (int i = 0; i < 4; ++i) {
      int ci = i * 4 + wave;
      gl2lds16(W + (size_t)(h * 8 + kt) * 8192 + ci * 512 + lane * 8,
               &tB[sel][ci * 512 + lane * 8]);
    }
  };

  f32x4 acc[2][4];
  for (int i = 0; i < 2; ++i)
    for (int j = 0; j < 4; ++j) acc[i][j] = (f32x4){0.f, 0.f, 0.f, 0.f};

  stage(0, 0);
  __syncthreads();
  for (int kt = 0; kt < 8; ++kt) {
    const int sel = kt & 1;
    if (kt < 7) stage(kt + 1, sel ^ 1);
    __builtin_amdgcn_s_setprio(1);
#pragma unroll
    for (int kk = 0; kk < 2; ++kk) {
      short8 af[2], bf[4];
#pragma unroll
      for (int mi = 0; mi < 2; ++mi) {
        int row = wm + mi * 16 + r15;
        af[mi] = *(short8*)&tA[sel][row * 64 + (((kk * 4 + hi) ^ (row & 7)) * 8)];
      }
#pragma unroll
      for (int ni = 0; ni < 4; ++ni) {
        int row = wn + ni * 16 + r15;
        bf[ni] = *(short8*)&tB[sel][row * 64 + (((kk * 4 + hi) ^ (row & 7)) * 8)];
      }
#pragma unroll
      for (int mi = 0; mi < 2; ++mi)
#pragma unroll
        for (int ni = 0; ni < 4; ++ni)
          acc[mi][ni] = __builtin_amdgcn_mfma_f32_16x16x32_bf16(
              af[mi], bf[ni], acc[mi][ni], 0, 0, 0);
    }
    __builtin_amdgcn_s_setprio(0);
    __syncthreads();
  }

  // epilogue: scatter into output panels
#pragma unroll
  for (int mi = 0; mi < 2; ++mi)
#pragma unroll
    for (int ni = 0; ni < 4; ++ni)
#pragma unroll
      for (int r = 0; r < 4; ++r) {
        int m = mt * 64 + wm + mi * 16 + hi * 4 + r;  // global A row
        int d = wn + ni * 16 + r15;                   // 0..127 within head
        int bq = m >> 10, q = m & 1023, t = q >> 7, pr = q & 127;
        size_t pbase = (size_t)((bq * 4 + h) * 8 + t) * 16384;
        unsigned short v = f2b(acc[mi][ni][r]);
        if (!tr)
          C[pbase + pr * 128 + (((d >> 3) ^ (pr & 7)) * 8) + (d & 7)] = v;
        else
          C[pbase + d * 128 + (((pr >> 3) ^ (d & 7)) * 8) + (pr & 7)] = v;
      }
}

// ---------------- K2: QK^T + mask + no-max softmax + coalesced attn write ----
__global__ __launch_bounds__(512, 4) void attn_s_kernel(
    const unsigned short* __restrict__ Qb, const unsigned short* __restrict__ Kb,
    const unsigned int* __restrict__ maskp, const float* __restrict__ qmask,
    float* __restrict__ attn) {
  __shared__ unsigned short tQ[32 * 128];     // 8KB
  __shared__ unsigned short buf0[128 * 128];  // 32KB (reused as f32 S-staging)
  __shared__ unsigned short buf1[128 * 128];  // 32KB (reused as f32 S-staging)
  __shared__ float redsum[32][8];             // 1KB
  const int L = blockIdx.x;
  const int r_ = L & 7;
  const int j_ = L >> 3;
  const int qt = j_ & 31;
  const int hb = (j_ >> 5) * 8 + r_;  // = h*8 + b
  const int h = hb >> 3, b = hb & 7;
  const int q0 = qt * 32;
  const int tid = threadIdx.x;
  const int lane = tid & 63, wave = tid >> 6;
  const int r15 = lane & 15, hi = lane >> 4;

  auto stageK = [&](int t, unsigned short* buf) {
    const unsigned short* p = Kb + (size_t)((b * 4 + h) * 8 + t) * 16384;
#pragma unroll
    for (int i = 0; i < 4; ++i) {
      int ci = i * 8 + wave;
      gl2lds16(p + ci * 512 + lane * 8, buf + ci * 512 + lane * 8);
    }
  };
  {  // stage Q: 8KB contiguous sub-slice of its panel
    const unsigned short* p =
        Qb + (size_t)((b * 4 + h) * 8 + (q0 >> 7)) * 16384 + (q0 & 127) * 128;
    gl2lds16(p + wave * 512 + lane * 8, tQ + wave * 512 + lane * 8);
  }
  stageK(0, buf0);
  __syncthreads();

  f32x4 acc[2][8];
#pragma unroll
  for (int g = 0; g < 2; ++g)
#pragma unroll
    for (int t = 0; t < 8; ++t) acc[g][t] = (f32x4){0.f, 0.f, 0.f, 0.f};

#pragma unroll
  for (int t = 0; t < 8; ++t) {
    if (t < 7) stageK(t + 1, (t & 1) ? buf0 : buf1);
    const unsigned short* kb = (t & 1) ? buf1 : buf0;
    __builtin_amdgcn_s_setprio(1);
#pragma unroll
    for (int ks = 0; ks < 4; ++ks) {
      const int sw = ((ks * 4 + hi) ^ (r15 & 7)) * 8;
      short8 bk = *(const short8*)&kb[(wave * 16 + r15) * 128 + sw];
#pragma unroll
      for (int g = 0; g < 2; ++g) {
        short8 aqv = *(const short8*)&tQ[(g * 16 + r15) * 128 + sw];
        acc[g][t] = __builtin_amdgcn_mfma_f32_16x16x32_bf16(aqv, bk, acc[g][t], 0, 0, 0);
      }
    }
    __builtin_amdgcn_s_setprio(0);
    __syncthreads();
  }

  // ---- mask + scale + exp (no max subtraction: |s| small, masked -> exp=0) ----
  const float isd = 0.08838834764831845f;
  const int sh = (wave & 1) * 16 + r15;
#pragma unroll
  for (int g = 0; g < 2; ++g)
#pragma unroll
    for (int r = 0; r < 4; ++r) {
      const unsigned int* mrow =
          maskp + ((size_t)(b * NSQ) + q0 + g * 16 + hi * 4 + r) * 32 + (wave >> 1) * 8;
      uint4 wa = *(const uint4*)mrow;
      uint4 wb = *(const uint4*)(mrow + 4);
      unsigned int mw8[8] = {wa.x, wa.y, wa.z, wa.w, wb.x, wb.y, wb.z, wb.w};
      float sm = 0.f;
#pragma unroll
      for (int t = 0; t < 8; ++t) {
        unsigned int bit = (mw8[t] >> sh) & 1u;
        float s = acc[g][t][r] * isd;
        float e = __expf(bit ? -4294967296.0f : s);
        acc[g][t][r] = e;
        sm += e;
      }
      sm += __shfl_xor(sm, 1);
      sm += __shfl_xor(sm, 2);
      sm += __shfl_xor(sm, 4);
      sm += __shfl_xor(sm, 8);
      if (r15 == 0) redsum[g * 16 + hi * 4 + r][wave] = sm;
    }
  __syncthreads();
#pragma unroll
  for (int g = 0; g < 2; ++g)
#pragma unroll
    for (int r = 0; r < 4; ++r) {
      float4 a = *(float4*)&redsum[g * 16 + hi * 4 + r][0];
      float4 c = *(float4*)&redsum[g * 16 + hi * 4 + r][4];
      float sum = (a.x + a.y + a.z + a.w) + (c.x + c.y + c.z + c.w);
      float scl = qmask[b * NSQ + q0 + g * 16 + hi * 4 + r] / sum;
#pragma unroll
      for (int t = 0; t < 8; ++t) acc[g][t][r] *= scl;
    }

  // ---- coalesced attn write: LDS ping-pong staging, 512B-segment stores ----
  // Sb[t&1] is a [32][132] f32 tile (16.9KB, fits in dead buf0/buf1).
  {
    float* Sb0 = (float*)buf0;
    float* Sb1 = (float*)buf1;
    const int row = tid >> 4, l16 = tid & 15;
    float* orow = attn + ((size_t)hb * NSQ + q0 + row) * NSK + l16 * 8;
    // write t=0
#pragma unroll
    for (int g = 0; g < 2; ++g)
#pragma unroll
      for (int r = 0; r < 4; ++r)
        Sb0[(g * 16 + hi * 4 + r) * 132 + wave * 16 + r15] = acc[g][0][r];
    __syncthreads();
#pragma unroll
    for (int t = 0; t < 8; ++t) {
      if (t < 7) {
        float* Sn = ((t + 1) & 1) ? Sb1 : Sb0;
#pragma unroll
        for (int g = 0; g < 2; ++g)
#pragma unroll
          for (int r = 0; r < 4; ++r)
            Sn[(g * 16 + hi * 4 + r) * 132 + wave * 16 + r15] = acc[g][t + 1][r];
      }
      const float* Sc = (t & 1) ? Sb1 : Sb0;
      f32x4 v0 = *(const f32x4*)&Sc[row * 132 + l16 * 8];
      f32x4 v1 = *(const f32x4*)&Sc[row * 132 + l16 * 8 + 4];
      *(f32x4*)(orow + t * 128) = v0;
      *(f32x4*)(orow + t * 128 + 4) = v1;
      __syncthreads();
    }
  }
}

// ---------------- K3: out = attn @ V  (64x128 tile, BK=128, 512 blocks) ------
__global__ __launch_bounds__(256) void pv_gemm(const float* __restrict__ attn,
                                               const unsigned short* __restrict__ Vtb,
                                               unsigned short* __restrict__ outh) {
  __shared__ unsigned short tA[64 * 128];   // 16KB swizzled P tile
  __shared__ unsigned short tB[128 * 128];  // 32KB V panel (linear copy)
  const int L = blockIdx.x;  // 512 blocks; bid%8 const per (h,b)
  const int r_ = L & 7, q_ = (L >> 3) & 15, s_ = L >> 7;
  const int hb = s_ * 8 + r_;
  const int h = hb >> 3, b = hb & 7;
  const int m0 = q_ * 64;
  const int tid = threadIdx.x;
  const int lane = tid & 63;
  const int wave = tid >> 6;
  const int wn = wave * 32;
  const int r15 = lane & 15, hi = lane >> 4;
  const float* Abase = attn + (size_t)hb * NSQ * NSK;

  f32x4 acc[4][2];
  for (int i = 0; i < 4; ++i)
    for (int j = 0; j < 2; ++j) acc[i][j] = (f32x4){0.f, 0.f, 0.f, 0.f};

  for (int kt = 0; kt < 8; ++kt) {
    {
      const unsigned short* p = Vtb + (size_t)((b * 4 + h) * 8 + kt) * 16384;
#pragma unroll
      for (int i = 0; i < 8; ++i) {
        int ci = i * 4 + wave;
        gl2lds16(p + ci * 512 + lane * 8, tB + ci * 512 + lane * 8);
      }
    }
#pragma unroll
    for (int it = 0; it < 4; ++it) {
      int idx = it * 256 + tid;
      int row = idx >> 4, c = idx & 15;
      const float* sa = Abase + (size_t)(m0 + row) * NSK + kt * 128 + c * 8;
      f32x4 a0 = *(const f32x4*)sa;
      f32x4 a1 = *(const f32x4*)(sa + 4);
      *(short8*)&tA[row * 128 + ((c ^ (row & 7)) * 8)] = pack8v(a0, a1);
    }
    __syncthreads();
    __builtin_amdgcn_s_setprio(1);
#pragma unroll
    for (int ks = 0; ks < 4; ++ks) {
      short8 af[4], bf[2];
#pragma unroll
      for (int mi = 0; mi < 4; ++mi) {
        int row = mi * 16 + r15;
        af[mi] = *(short8*)&tA[row * 128 + (((ks * 4 + hi) ^ (row & 7)) * 8)];
      }
#pragma unroll
      for (int ni = 0; ni < 2; ++ni) {
        int row = wn + ni * 16 + r15;
        bf[ni] = *(short8*)&tB[row * 128 + (((ks * 4 + hi) ^ (row & 7)) * 8)];
      }
#pragma unroll
      for (int mi = 0; mi < 4; ++mi)
#pragma unroll
        for (int ni = 0; ni < 2; ++ni)
          acc[mi][ni] = __builtin_amdgcn_mfma_f32_16x16x32_bf16(
              af[mi], bf[ni], acc[mi][ni], 0, 0, 0);
    }
    __builtin_amdgcn_s_setprio(0);
    __syncthreads();
  }
#pragma unroll
  for (int mi = 0; mi < 4; ++mi)
#pragma unroll
    for (int ni = 0; ni < 2; ++ni)
#pragma unroll
      for (int r = 0; r < 4; ++r) {
        int m = m0 + mi * 16 + hi * 4 + r;
        int n = wn + ni * 16 + r15;
        outh[(size_t)(b * NSQ + m) * NHID + h * NDH + n] = f2b(acc[mi][ni][r]);
      }
}

// ---------------- K4: residual + LayerNorm: result = LN(outh + dec) ----------
__global__ __launch_bounds__(256) void ln_kernel(const unsigned short* __restrict__ outh,
                                                 const float* __restrict__ dec,
                                                 const float* __restrict__ gamma,
                                                 const float* __restrict__ beta,
                                                 float* __restrict__ result) {
  const int tid = threadIdx.x;
  const int lane = tid & 63, wave = tid >> 6;
  const size_t row = (size_t)blockIdx.x * 4 + wave;
  const unsigned short* xr = outh + row * NHID;
  const float* dr = dec + row * NHID;
  float v[8];
  float s = 0.f;
  short8 xv = *(const short8*)(xr + lane * 8);
  for (int j = 0; j < 2; ++j) {
    float4 d = *(const float4*)(dr + lane * 8 + j * 4);
    v[j * 4 + 0] = b2f((unsigned short)xv[j * 4 + 0]) + d.x;
    v[j * 4 + 1] = b2f((unsigned short)xv[j * 4 + 1]) + d.y;
    v[j * 4 + 2] = b2f((unsigned short)xv[j * 4 + 2]) + d.z;
    v[j * 4 + 3] = b2f((unsigned short)xv[j * 4 + 3]) + d.w;
  }
  for (int j = 0; j < 8; ++j) s += v[j];
  for (int off = 32; off > 0; off >>= 1) s += __shfl_xor(s, off);
  float mu = s * (1.f / 512.f);
  float s2 = 0.f;
  for (int j = 0; j < 8; ++j) {
    float d = v[j] - mu;
    s2 += d * d;
  }
  for (int off = 32; off > 0; off >>= 1) s2 += __shfl_xor(s2, off);
  float rstd = rsqrtf(s2 * (1.f / 512.f) + 1e-5f);
  float* out = result + row * NHID;
  for (int j = 0; j < 2; ++j) {
    float4 g = *(const float4*)(gamma + lane * 8 + j * 4);
    float4 bt = *(const float4*)(beta + lane * 8 + j * 4);
    float4 o;
    o.x = (v[j * 4 + 0] - mu) * rstd * g.x + bt.x;
    o.y = (v[j * 4 + 1] - mu) * rstd * g.y + bt.y;
    o.z = (v[j * 4 + 2] - mu) * rstd * g.z + bt.z;
    o.w = (v[j * 4 + 3] - mu) * rstd * g.w + bt.w;
    *(float4*)(out + lane * 8 + j * 4) = o;
  }
}

extern "C" void kernel_launch(void* const* d_in, const int* in_sizes, int n_in,
                              void* d_out, int out_size, void* d_ws, size_t ws_size,
                              hipStream_t stream) {
  const float* memory = (const float*)d_in[0];
  const float* dec = (const float*)d_in[1];
  const int* mask = (const int*)d_in[2];
  const float* qmask = (const float*)d_in[3];
  const float* Wk = (const float*)d_in[4];
  const float* Wv = (const float*)d_in[5];
  const float* Wq = (const float*)d_in[6];
  const float* gamma = (const float*)d_in[7];
  const float* beta = (const float*)d_in[8];

  char* ws = (char*)d_ws;
  unsigned short* decBb = (unsigned short*)(ws + 0);        // 8 MB (blocked)
  unsigned short* memBb = (unsigned short*)(ws + 8388608);  // 8 MB (blocked)
  unsigned short* outh = (unsigned short*)(ws + 0);  // 8 MB bf16, overlays decBb
  unsigned short* WB = (unsigned short*)(ws + 16777216);    // 1.5 MB (Wq|Wk|Wv)
  unsigned short* QKVb = (unsigned short*)(ws + 18350080);  // 24 MB panels Q|K|Vt
  unsigned int* maskw = (unsigned int*)(ws + 43515904);     // 1 MB (permuted words)

  unsigned short* Qb = QKVb;
  unsigned short* Kb = QKVb + 4194304;
  unsigned short* Vtb = QKVb + 8388608;

  float* resultp = (float*)d_out;            // (B,SQ,H)    = 4194304 f32
  float* attnp = resultp + 4194304;          // (NH*B,SQ,SK)= 33554432 f32

  cvt_pack<<<dim3(5504), dim3(256), 0, stream>>>(dec, memory, Wq, Wk, Wv, mask,
                                                 decBb, memBb, WB, maskw);
  proj_gemm_all<<<dim3(128, 4, 3), dim3(256), 0, stream>>>(decBb, memBb, WB, QKVb);

  attn_s_kernel<<<dim3(1024), dim3(512), 0, stream>>>(Qb, Kb, maskw, qmask, attnp);
  pv_gemm<<<dim3(512), dim3(256), 0, stream>>>(attnp, Vtb, outh);
  ln_kernel<<<dim3(2048), dim3(256), 0, stream>>>(outh, dec, gamma, beta, resultp);
}

// Round 16
// 114.090 us; speedup vs baseline: 1.0700x; 1.0700x over previous
//
#include <hip/hip_runtime.h>
#include <hip/hip_bf16.h>
#include <stdint.h>

#define NB 8
#define NSQ 1024
#define NSK 1024
#define NHID 512
#define NHEAD 4
#define NDH 128

typedef __attribute__((ext_vector_type(8))) short short8;
typedef __attribute__((ext_vector_type(4))) float f32x4;
typedef __attribute__((ext_vector_type(4))) int i32x4;

__device__ __forceinline__ unsigned short f2b(float f) {
  unsigned int u = __builtin_bit_cast(unsigned int, f);
  u = u + 0x7FFFu + ((u >> 16) & 1u);
  return (unsigned short)(u >> 16);
}

__device__ __forceinline__ float b2f(unsigned short s) {
  unsigned int u = ((unsigned int)s) << 16;
  return __builtin_bit_cast(float, u);
}

__device__ __forceinline__ short8 pack8v(f32x4 a, f32x4 b) {
  short8 o;
  o[0] = (short)f2b(a.x); o[1] = (short)f2b(a.y);
  o[2] = (short)f2b(a.z); o[3] = (short)f2b(a.w);
  o[4] = (short)f2b(b.x); o[5] = (short)f2b(b.y);
  o[6] = (short)f2b(b.z); o[7] = (short)f2b(b.w);
  return o;
}

// async global->LDS, 16B per lane; lds dest = wave-uniform base + lane*16
__device__ __forceinline__ void gl2lds16(const unsigned short* g, unsigned short* l) {
  __builtin_amdgcn_global_load_lds(
      (const __attribute__((address_space(1))) void*)g,
      (__attribute__((address_space(3))) void*)l, 16, 0, 0);
}

// ---------------- K0: fused f32->panel convert + mask bit-pack ---------------
__global__ __launch_bounds__(256) void cvt_pack(
    const float* __restrict__ dec, const float* __restrict__ mem,
    const float* __restrict__ Wq, const float* __restrict__ Wk,
    const float* __restrict__ Wv, const int* __restrict__ mask,
    unsigned short* __restrict__ decB, unsigned short* __restrict__ memB,
    unsigned short* __restrict__ WB, unsigned int* __restrict__ mw) {
  const int bid = blockIdx.x, tid = threadIdx.x;
  if (bid >= 4480) {
    int w = (bid - 4480) * 256 + tid;  // word index, 262144 total
    const int* src = mask + (size_t)w * 32;
    unsigned int bits = 0;
#pragma unroll
    for (int j = 0; j < 32; j += 4) {
      i32x4 v = *(const i32x4*)(src + j);
      bits |= (v.x ? 1u << j : 0u) | (v.y ? 1u << (j + 1) : 0u) |
              (v.z ? 1u << (j + 2) : 0u) | (v.w ? 1u << (j + 3) : 0u);
    }
    int row = w >> 5, wi = w & 31;
    mw[(size_t)row * 32 + ((wi & 3) * 8 + (wi >> 2))] = bits;
    return;
  }
  const float* src;
  unsigned short* dst;
  int base_row;
  if (bid < 2048) { src = dec; dst = decB; base_row = bid * 4; }
  else if (bid < 4096) { src = mem; dst = memB; base_row = (bid - 2048) * 4; }
  else {
    int w = bid - 4096;          // 0..383
    int wi = w >> 7;             // which weight
    src = (wi == 0) ? Wq : (wi == 1) ? Wk : Wv;
    dst = WB + (size_t)wi * 262144;
    base_row = (w & 127) * 4;
  }
  const int row = base_row + (tid >> 6);
  const int kpos = (tid & 63) * 8;
  const float* s = src + (size_t)row * 512 + kpos;
  f32x4 a0 = *(const f32x4*)s;
  f32x4 a1 = *(const f32x4*)(s + 4);
  const int mt = row >> 7, kt = kpos >> 6, pr = row & 127, c = (kpos & 63) >> 3;
  *(short8*)&dst[(size_t)(mt * 8 + kt) * 8192 + pr * 64 + ((c ^ (pr & 7)) * 8)] =
      pack8v(a0, a1);
}

// ---------------- K1: all 3 projection GEMMs, one launch (128,4,3) -----------
// 64x128 tiles: 3 blocks/CU (48KB LDS) so the per-kt barrier drain overlaps.
__global__ __launch_bounds__(256) void proj_gemm_all(
    const unsigned short* __restrict__ decB, const unsigned short* __restrict__ memB,
    const unsigned short* __restrict__ WB, unsigned short* __restrict__ Cb) {
  __shared__ unsigned short tA[2][4096];   // 16KB: 64 rows x 64 k, dbuf
  __shared__ unsigned short tB[2][8192];   // 32KB: 128 rows x 64 k, dbuf
  const int z = blockIdx.z;
  const int mt = blockIdx.x, h = blockIdx.y;  // mt: 64-row tile index (0..127)
  const unsigned short* A = (z == 0) ? decB : memB;
  const unsigned short* W = WB + (size_t)z * 262144;
  unsigned short* C = Cb + (size_t)z * 4194304;
  const bool tr = (z == 2);
  const int tid = threadIdx.x, lane = tid & 63, wave = tid >> 6;
  const int wm = (wave & 1) * 32, wn = (wave >> 1) * 64;
  const int r15 = lane & 15, hi = lane >> 4;

  // A sub-slab: panel (mt>>1, kt), rows (mt&1)*64..+64 = contiguous 8KB
  auto stage = [&](int kt, int sel) {
    const unsigned short* ap =
        A + (size_t)((mt >> 1) * 8 + kt) * 8192 + (mt & 1) * 4096;
#pragma unroll
    for (int i = 0; i < 2; ++i) {
      int ci = i * 4 + wave;
      gl2lds16(ap + ci * 512 + lane * 8, &tA[sel][ci * 512 + lane * 8]);
    }
#pragma unroll
    for (int i = 0; i < 4; ++i) {
      int ci = i * 4 + wave;
      gl2lds16(W + (size_t)(h * 8 + kt) * 8192 + ci * 512 + lane * 8,
               &tB[sel][ci * 512 + lane * 8]);
    }
  };

  f32x4 acc[2][4];
  for (int i = 0; i < 2; ++i)
    for (int j = 0; j < 4; ++j) acc[i][j] = (f32x4){0.f, 0.f, 0.f, 0.f};

  stage(0, 0);
  __syncthreads();
  for (int kt = 0; kt < 8; ++kt) {
    const int sel = kt & 1;
    if (kt < 7) stage(kt + 1, sel ^ 1);
    __builtin_amdgcn_s_setprio(1);
#pragma unroll
    for (int kk = 0; kk < 2; ++kk) {
      short8 af[2], bf[4];
#pragma unroll
      for (int mi = 0; mi < 2; ++mi) {
        int row = wm + mi * 16 + r15;
        af[mi] = *(short8*)&tA[sel][row * 64 + (((kk * 4 + hi) ^ (row & 7)) * 8)];
      }
#pragma unroll
      for (int ni = 0; ni < 4; ++ni) {
        int row = wn + ni * 16 + r15;
        bf[ni] = *(short8*)&tB[sel][row * 64 + (((kk * 4 + hi) ^ (row & 7)) * 8)];
      }
#pragma unroll
      for (int mi = 0; mi < 2; ++mi)
#pragma unroll
        for (int ni = 0; ni < 4; ++ni)
          acc[mi][ni] = __builtin_amdgcn_mfma_f32_16x16x32_bf16(
              af[mi], bf[ni], acc[mi][ni], 0, 0, 0);
    }
    __builtin_amdgcn_s_setprio(0);
    __syncthreads();
  }

  // epilogue: scatter into output panels
#pragma unroll
  for (int mi = 0; mi < 2; ++mi)
#pragma unroll
    for (int ni = 0; ni < 4; ++ni)
#pragma unroll
      for (int r = 0; r < 4; ++r) {
        int m = mt * 64 + wm + mi * 16 + hi * 4 + r;  // global A row
        int d = wn + ni * 16 + r15;                   // 0..127 within head
        int bq = m >> 10, q = m & 1023, t = q >> 7, pr = q & 127;
        size_t pbase = (size_t)((bq * 4 + h) * 8 + t) * 16384;
        unsigned short v = f2b(acc[mi][ni][r]);
        if (!tr)
          C[pbase + pr * 128 + (((d >> 3) ^ (pr & 7)) * 8) + (d & 7)] = v;
        else
          C[pbase + d * 128 + (((pr >> 3) ^ (d & 7)) * 8) + (pr & 7)] = v;
      }
}

// ---------------- K2: QK^T + mask + no-max softmax + attn f32 write ----------
__global__ __launch_bounds__(512, 4) void attn_s_kernel(
    const unsigned short* __restrict__ Qb, const unsigned short* __restrict__ Kb,
    const unsigned int* __restrict__ maskp, const float* __restrict__ qmask,
    float* __restrict__ attn) {
  __shared__ unsigned short tQ[32 * 128];     // 8KB
  __shared__ unsigned short buf0[128 * 128];  // 32KB
  __shared__ unsigned short buf1[128 * 128];  // 32KB
  __shared__ float redsum[32][8];             // 1KB
  const int L = blockIdx.x;
  const int r_ = L & 7;
  const int j_ = L >> 3;
  const int qt = j_ & 31;
  const int hb = (j_ >> 5) * 8 + r_;  // = h*8 + b
  const int h = hb >> 3, b = hb & 7;
  const int q0 = qt * 32;
  const int tid = threadIdx.x;
  const int lane = tid & 63, wave = tid >> 6;
  const int r15 = lane & 15, hi = lane >> 4;

  auto stageK = [&](int t, unsigned short* buf) {
    const unsigned short* p = Kb + (size_t)((b * 4 + h) * 8 + t) * 16384;
#pragma unroll
    for (int i = 0; i < 4; ++i) {
      int ci = i * 8 + wave;
      gl2lds16(p + ci * 512 + lane * 8, buf + ci * 512 + lane * 8);
    }
  };
  {  // stage Q: 8KB contiguous sub-slice of its panel
    const unsigned short* p =
        Qb + (size_t)((b * 4 + h) * 8 + (q0 >> 7)) * 16384 + (q0 & 127) * 128;
    gl2lds16(p + wave * 512 + lane * 8, tQ + wave * 512 + lane * 8);
  }
  stageK(0, buf0);
  __syncthreads();

  f32x4 acc[2][8];
#pragma unroll
  for (int g = 0; g < 2; ++g)
#pragma unroll
    for (int t = 0; t < 8; ++t) acc[g][t] = (f32x4){0.f, 0.f, 0.f, 0.f};

#pragma unroll
  for (int t = 0; t < 8; ++t) {
    if (t < 7) stageK(t + 1, (t & 1) ? buf0 : buf1);
    const unsigned short* kb = (t & 1) ? buf1 : buf0;
    __builtin_amdgcn_s_setprio(1);
#pragma unroll
    for (int ks = 0; ks < 4; ++ks) {
      const int sw = ((ks * 4 + hi) ^ (r15 & 7)) * 8;
      short8 bk = *(const short8*)&kb[(wave * 16 + r15) * 128 + sw];
#pragma unroll
      for (int g = 0; g < 2; ++g) {
        short8 aqv = *(const short8*)&tQ[(g * 16 + r15) * 128 + sw];
        acc[g][t] = __builtin_amdgcn_mfma_f32_16x16x32_bf16(aqv, bk, acc[g][t], 0, 0, 0);
      }
    }
    __builtin_amdgcn_s_setprio(0);
    __syncthreads();
  }

  // ---- mask + scale + exp (no max subtraction: |s| small, masked -> exp=0) ----
  const float isd = 0.08838834764831845f;
  const int sh = (wave & 1) * 16 + r15;
#pragma unroll
  for (int g = 0; g < 2; ++g)
#pragma unroll
    for (int r = 0; r < 4; ++r) {
      const unsigned int* mrow =
          maskp + ((size_t)(b * NSQ) + q0 + g * 16 + hi * 4 + r) * 32 + (wave >> 1) * 8;
      uint4 wa = *(const uint4*)mrow;
      uint4 wb = *(const uint4*)(mrow + 4);
      unsigned int mw8[8] = {wa.x, wa.y, wa.z, wa.w, wb.x, wb.y, wb.z, wb.w};
      float sm = 0.f;
#pragma unroll
      for (int t = 0; t < 8; ++t) {
        unsigned int bit = (mw8[t] >> sh) & 1u;
        float s = acc[g][t][r] * isd;
        float e = __expf(bit ? -4294967296.0f : s);
        acc[g][t][r] = e;
        sm += e;
      }
      sm += __shfl_xor(sm, 1);
      sm += __shfl_xor(sm, 2);
      sm += __shfl_xor(sm, 4);
      sm += __shfl_xor(sm, 8);
      if (r15 == 0) redsum[g * 16 + hi * 4 + r][wave] = sm;
    }
  __syncthreads();
#pragma unroll
  for (int g = 0; g < 2; ++g)
#pragma unroll
    for (int r = 0; r < 4; ++r) {
      float4 a = *(float4*)&redsum[g * 16 + hi * 4 + r][0];
      float4 c = *(float4*)&redsum[g * 16 + hi * 4 + r][4];
      float sum = (a.x + a.y + a.z + a.w) + (c.x + c.y + c.z + c.w);
      float scl = qmask[b * NSQ + q0 + g * 16 + hi * 4 + r] / sum;
#pragma unroll
      for (int t = 0; t < 8; ++t) acc[g][t][r] *= scl;
    }

  // ---- write attn f32 ----
#pragma unroll
  for (int g = 0; g < 2; ++g) {
    float* abase =
        attn + ((size_t)hb * NSQ + q0 + g * 16 + hi * 4) * NSK + wave * 16 + r15;
#pragma unroll
    for (int t = 0; t < 8; ++t)
#pragma unroll
      for (int r = 0; r < 4; ++r) abase[(r << 10) + t * 128] = acc[g][t][r];
  }
}

// ---------------- K3: out = attn @ V  (64x128 tile, BK=128, 512 blocks) ------
// outh written as bf16 (halves traffic into ln).
__global__ __launch_bounds__(256) void pv_gemm(const float* __restrict__ attn,
                                               const unsigned short* __restrict__ Vtb,
                                               unsigned short* __restrict__ outh) {
  __shared__ unsigned short tA[64 * 128];   // 16KB swizzled P tile
  __shared__ unsigned short tB[128 * 128];  // 32KB V panel (linear copy)
  const int L = blockIdx.x;  // 512 blocks; bid%8 const per (h,b)
  const int r_ = L & 7, q_ = (L >> 3) & 15, s_ = L >> 7;
  const int hb = s_ * 8 + r_;
  const int h = hb >> 3, b = hb & 7;
  const int m0 = q_ * 64;
  const int tid = threadIdx.x;
  const int lane = tid & 63;
  const int wave = tid >> 6;
  const int wn = wave * 32;
  const int r15 = lane & 15, hi = lane >> 4;
  const float* Abase = attn + (size_t)hb * NSQ * NSK;

  f32x4 acc[4][2];
  for (int i = 0; i < 4; ++i)
    for (int j = 0; j < 2; ++j) acc[i][j] = (f32x4){0.f, 0.f, 0.f, 0.f};

  for (int kt = 0; kt < 8; ++kt) {
    // stage V panel: contiguous 32KB memcpy
    {
      const unsigned short* p = Vtb + (size_t)((b * 4 + h) * 8 + kt) * 16384;
#pragma unroll
      for (int i = 0; i < 8; ++i) {
        int ci = i * 4 + wave;
        gl2lds16(p + ci * 512 + lane * 8, tB + ci * 512 + lane * 8);
      }
    }
    // stage A tile: 64 q x 128 k f32 -> bf16 swizzled
#pragma unroll
    for (int it = 0; it < 4; ++it) {
      int idx = it * 256 + tid;
      int row = idx >> 4, c = idx & 15;
      const float* sa = Abase + (size_t)(m0 + row) * NSK + kt * 128 + c * 8;
      f32x4 a0 = *(const f32x4*)sa;
      f32x4 a1 = *(const f32x4*)(sa + 4);
      *(short8*)&tA[row * 128 + ((c ^ (row & 7)) * 8)] = pack8v(a0, a1);
    }
    __syncthreads();
    __builtin_amdgcn_s_setprio(1);
#pragma unroll
    for (int ks = 0; ks < 4; ++ks) {
      short8 af[4], bf[2];
#pragma unroll
      for (int mi = 0; mi < 4; ++mi) {
        int row = mi * 16 + r15;
        af[mi] = *(short8*)&tA[row * 128 + (((ks * 4 + hi) ^ (row & 7)) * 8)];
      }
#pragma unroll
      for (int ni = 0; ni < 2; ++ni) {
        int row = wn + ni * 16 + r15;
        bf[ni] = *(short8*)&tB[row * 128 + (((ks * 4 + hi) ^ (row & 7)) * 8)];
      }
#pragma unroll
      for (int mi = 0; mi < 4; ++mi)
#pragma unroll
        for (int ni = 0; ni < 2; ++ni)
          acc[mi][ni] = __builtin_amdgcn_mfma_f32_16x16x32_bf16(
              af[mi], bf[ni], acc[mi][ni], 0, 0, 0);
    }
    __builtin_amdgcn_s_setprio(0);
    __syncthreads();
  }
#pragma unroll
  for (int mi = 0; mi < 4; ++mi)
#pragma unroll
    for (int ni = 0; ni < 2; ++ni)
#pragma unroll
      for (int r = 0; r < 4; ++r) {
        int m = m0 + mi * 16 + hi * 4 + r;
        int n = wn + ni * 16 + r15;
        outh[(size_t)(b * NSQ + m) * NHID + h * NDH + n] = f2b(acc[mi][ni][r]);
      }
}

// ---------------- K4: residual + LayerNorm: result = LN(outh + dec) ----------
__global__ __launch_bounds__(256) void ln_kernel(const unsigned short* __restrict__ outh,
                                                 const float* __restrict__ dec,
                                                 const float* __restrict__ gamma,
                                                 const float* __restrict__ beta,
                                                 float* __restrict__ result) {
  const int tid = threadIdx.x;
  const int lane = tid & 63, wave = tid >> 6;
  const size_t row = (size_t)blockIdx.x * 4 + wave;
  const unsigned short* xr = outh + row * NHID;
  const float* dr = dec + row * NHID;
  float v[8];
  float s = 0.f;
  short8 xv = *(const short8*)(xr + lane * 8);
  for (int j = 0; j < 2; ++j) {
    float4 d = *(const float4*)(dr + lane * 8 + j * 4);
    v[j * 4 + 0] = b2f((unsigned short)xv[j * 4 + 0]) + d.x;
    v[j * 4 + 1] = b2f((unsigned short)xv[j * 4 + 1]) + d.y;
    v[j * 4 + 2] = b2f((unsigned short)xv[j * 4 + 2]) + d.z;
    v[j * 4 + 3] = b2f((unsigned short)xv[j * 4 + 3]) + d.w;
  }
  for (int j = 0; j < 8; ++j) s += v[j];
  for (int off = 32; off > 0; off >>= 1) s += __shfl_xor(s, off);
  float mu = s * (1.f / 512.f);
  float s2 = 0.f;
  for (int j = 0; j < 8; ++j) {
    float d = v[j] - mu;
    s2 += d * d;
  }
  for (int off = 32; off > 0; off >>= 1) s2 += __shfl_xor(s2, off);
  float rstd = rsqrtf(s2 * (1.f / 512.f) + 1e-5f);
  float* out = result + row * NHID;
  for (int j = 0; j < 2; ++j) {
    float4 g = *(const float4*)(gamma + lane * 8 + j * 4);
    float4 bt = *(const float4*)(beta + lane * 8 + j * 4);
    float4 o;
    o.x = (v[j * 4 + 0] - mu) * rstd * g.x + bt.x;
    o.y = (v[j * 4 + 1] - mu) * rstd * g.y + bt.y;
    o.z = (v[j * 4 + 2] - mu) * rstd * g.z + bt.z;
    o.w = (v[j * 4 + 3] - mu) * rstd * g.w + bt.w;
    *(float4*)(out + lane * 8 + j * 4) = o;
  }
}

extern "C" void kernel_launch(void* const* d_in, const int* in_sizes, int n_in,
                              void* d_out, int out_size, void* d_ws, size_t ws_size,
                              hipStream_t stream) {
  const float* memory = (const float*)d_in[0];
  const float* dec = (const float*)d_in[1];
  const int* mask = (const int*)d_in[2];
  const float* qmask = (const float*)d_in[3];
  const float* Wk = (const float*)d_in[4];
  const float* Wv = (const float*)d_in[5];
  const float* Wq = (const float*)d_in[6];
  const float* gamma = (const float*)d_in[7];
  const float* beta = (const float*)d_in[8];

  char* ws = (char*)d_ws;
  unsigned short* decBb = (unsigned short*)(ws + 0);        // 8 MB (blocked)
  unsigned short* memBb = (unsigned short*)(ws + 8388608);  // 8 MB (blocked)
  unsigned short* outh = (unsigned short*)(ws + 0);  // 8 MB bf16, overlays decBb
  unsigned short* WB = (unsigned short*)(ws + 16777216);    // 1.5 MB (Wq|Wk|Wv)
  unsigned short* QKVb = (unsigned short*)(ws + 18350080);  // 24 MB panels Q|K|Vt
  unsigned int* maskw = (unsigned int*)(ws + 43515904);     // 1 MB (permuted words)

  unsigned short* Qb = QKVb;
  unsigned short* Kb = QKVb + 4194304;
  unsigned short* Vtb = QKVb + 8388608;

  float* resultp = (float*)d_out;            // (B,SQ,H)    = 4194304 f32
  float* attnp = resultp + 4194304;          // (NH*B,SQ,SK)= 33554432 f32

  cvt_pack<<<dim3(5504), dim3(256), 0, stream>>>(dec, memory, Wq, Wk, Wv, mask,
                                                 decBb, memBb, WB, maskw);
  proj_gemm_all<<<dim3(128, 4, 3), dim3(256), 0, stream>>>(decBb, memBb, WB, QKVb);

  attn_s_kernel<<<dim3(1024), dim3(512), 0, stream>>>(Qb, Kb, maskw, qmask, attnp);
  pv_gemm<<<dim3(512), dim3(256), 0, stream>>>(attnp, Vtb, outh);
  ln_kernel<<<dim3(2048), dim3(256), 0, stream>>>(outh, dec, gamma, beta, resultp);
}